// Round 16
// baseline (831.411 us; speedup 1.0000x reference)
//
#include <hip/hip_runtime.h>
#include <hip/hip_fp8.h>
#include <hip/hip_fp16.h>
#include <stdint.h>

#define FP8_MAX_V 448.0f

typedef float f32x16 __attribute__((ext_vector_type(16)));
typedef int i32x4 __attribute__((ext_vector_type(4)));
typedef int i32x8 __attribute__((ext_vector_type(8)));

__device__ __forceinline__ uint8_t cvt_fp8(float v) {
    return __hip_cvt_float_to_fp8(fminf(fmaxf(v, -FP8_MAX_V), FP8_MAX_V),
                                  __HIP_SATFINITE, __HIP_E4M3);
}

// ---------------- probe weight transport dtype + init amax ----------------
__global__ void fp8lin_probe(const uint32_t* __restrict__ w, unsigned* __restrict__ flag,
                             unsigned* __restrict__ amax_bits) {
    __shared__ unsigned s32, s16, s4;
    if (threadIdx.x == 0) { s32 = 0u; s16 = 0u; s4 = 0u; *amax_bits = 0u; }
    __syncthreads();
    unsigned o32 = 0u, o16 = 0u, o4 = 0u;
    for (int i = threadIdx.x; i < 4096; i += 256) {
        uint32_t v = w[i];
        o32 |= v & 0x000FFFFFu;
        uint32_t h0 = v & 0xFFFFu, h1 = v >> 16;
        o16 |= (h0 & 0x7Fu) | (h1 & 0x7Fu);
        o4  |= (h0 & 0x0Fu) | (h1 & 0x0Fu);
    }
    atomicOr(&s32, o32); atomicOr(&s16, o16); atomicOr(&s4, o4);
    __syncthreads();
    if (threadIdx.x == 0)
        *flag = (s32 == 0u) ? 0u : (s16 == 0u) ? 1u : (s4 == 0u) ? 2u : 3u;
}

// ---------------- amax (per-tensor, exact) ----------------
__global__ void fp8lin_amax(const float4* __restrict__ x, unsigned* __restrict__ amax_bits, long n4) {
    float m = 0.f;
    long stride = (long)gridDim.x * blockDim.x;
    for (long i = blockIdx.x * (long)blockDim.x + threadIdx.x; i < n4; i += stride) {
        float4 v = x[i];
        m = fmaxf(m, fmaxf(fmaxf(fabsf(v.x), fabsf(v.y)), fmaxf(fabsf(v.z), fabsf(v.w))));
    }
#pragma unroll
    for (int o = 32; o; o >>= 1) m = fmaxf(m, __shfl_xor(m, o));
    if ((threadIdx.x & 63) == 0) atomicMax(amax_bits, __float_as_uint(m));
}

// ---- quantize x -> fp8 AND write directly in MFMA-fragment pack order ----
__global__ void fp8lin_quantpack(const float* __restrict__ x, const unsigned* __restrict__ amax_bits,
                                 uchar4* __restrict__ apack, int M, int K) {
    float s = fmaxf(__uint_as_float(*amax_bits), 1e-12f) / FP8_MAX_V;
    const int NKT = K >> 6;
    const long units = ((long)M * K) >> 2;
    long stride = (long)gridDim.x * blockDim.x;
    for (long u = blockIdx.x * (long)blockDim.x + threadIdx.x; u < units; u += stride) {
        long b2 = u & 7;
        long r = (u >> 3) & 31;
        long q = (u >> 8) & 1;
        long v = u >> 9;
        long row = (v / NKT) * 32 + r;
        long k = (v % NKT) * 64 + q * 32 + b2 * 4;
        float4 t = *(const float4*)(x + row * (long)K + k);
        uchar4 o;
        o.x = cvt_fp8(t.x / s); o.y = cvt_fp8(t.y / s);
        o.z = cvt_fp8(t.z / s); o.w = cvt_fp8(t.w / s);
        apack[u] = o;
    }
}

// ---- convert + PACK weight into MFMA-fragment order (same layout as apack) ----
__global__ void fp8lin_packw(const void* __restrict__ wsrc, const unsigned* __restrict__ flag,
                             uint8_t* __restrict__ pack, int N, int K) {
    const int NKT = K >> 6;
    const long units = ((long)N * K) >> 6;
    unsigned f = *flag;
    long stride = (long)gridDim.x * blockDim.x;
    for (long u = blockIdx.x * (long)blockDim.x + threadIdx.x; u < units; u += stride) {
        int r = (int)(u & 31);
        long v = u >> 5;
        long row = (v / NKT) * 32 + r;
        long kbase = (long)(v % NKT) * 64;
        uint32_t wv[16];
        if (f == 0u) {
            const float4* s = (const float4*)((const float*)wsrc + row * K + kbase);
#pragma unroll
            for (int i = 0; i < 16; ++i) {
                float4 t = s[i];
                wv[i] = (uint32_t)cvt_fp8(t.x) | ((uint32_t)cvt_fp8(t.y) << 8) |
                        ((uint32_t)cvt_fp8(t.z) << 16) | ((uint32_t)cvt_fp8(t.w) << 24);
            }
        } else if (f == 1u) {
            const __half* s = (const __half*)wsrc + row * K + kbase;
#pragma unroll
            for (int i = 0; i < 16; ++i) {
                uint32_t a = 0;
#pragma unroll
                for (int j = 0; j < 4; ++j) a |= (uint32_t)cvt_fp8(__half2float(s[4 * i + j])) << (8 * j);
                wv[i] = a;
            }
        } else if (f == 2u) {
            const uint16_t* s = (const uint16_t*)wsrc + row * K + kbase;
#pragma unroll
            for (int i = 0; i < 16; ++i) {
                uint32_t a = 0;
#pragma unroll
                for (int j = 0; j < 4; ++j)
                    a |= (uint32_t)cvt_fp8(__uint_as_float((uint32_t)s[4 * i + j] << 16)) << (8 * j);
                wv[i] = a;
            }
        } else {
            const uint32_t* s = (const uint32_t*)((const uint8_t*)wsrc + row * K + kbase);
#pragma unroll
            for (int i = 0; i < 16; ++i) wv[i] = s[i];
        }
        uint8_t* d0 = pack + (v * 64 + r) * 32;
        uint8_t* d1 = pack + (v * 64 + 32 + r) * 32;
        i32x4 lo0 = { (int)wv[0], (int)wv[1], (int)wv[2], (int)wv[3] };
        i32x4 lo1 = { (int)wv[4], (int)wv[5], (int)wv[6], (int)wv[7] };
        i32x4 hi0 = { (int)wv[8], (int)wv[9], (int)wv[10], (int)wv[11] };
        i32x4 hi1 = { (int)wv[12], (int)wv[13], (int)wv[14], (int)wv[15] };
        *(i32x4*)(d0) = lo0; *(i32x4*)(d0 + 16) = lo1;
        *(i32x4*)(d1) = hi0; *(i32x4*)(d1 + 16) = hi1;
    }
}

// ---- fp8 GEMM: 256x128, 4 waves, MX 32x32x64 — no barriers/LDS, pipelined regs ----
// A/B vs R15: ONLY change is nontemporal -> plain output stores. R4 (plain) had
// FETCH=471MB; R5..R15 (nt) had 1.08-1.10GB = inputs + ~2x output: nt bypasses
// L2 write-aggregation -> partial-line RMW fetches at the controller. Testing
// whether that RMW traffic paces the K-loop (hbm at 2.7TB/s, not saturated).
#define BM 256
#define BN 128
#define BK 64

#define LDU(bv, ub, t) do {                                            \
    const uint8_t* _p = (ub) + (size_t)(t) * 2048 + voff;              \
    i32x4 _l0 = *(const i32x4*)(_p);                                   \
    i32x4 _l1 = *(const i32x4*)(_p + 16);                              \
    bv[0] = _l0[0]; bv[1] = _l0[1]; bv[2] = _l0[2]; bv[3] = _l0[3];    \
    bv[4] = _l1[0]; bv[5] = _l1[1]; bv[6] = _l1[2]; bv[7] = _l1[3];    \
} while (0)

#define WAITVM(N) asm volatile("s_waitcnt vmcnt(" #N ")" ::: "memory")

#define MFMA_MX(A, B, C) __builtin_amdgcn_mfma_scale_f32_32x32x64_f8f6f4( \
    (A), (B), (C), 0, 0, 0, (int)0x7f7f7f7f, 0, (int)0x7f7f7f7f)

#define P1(B0, B1) do {                               \
    __builtin_amdgcn_s_setprio(1);                    \
    acc[0][0] = MFMA_MX(a0, B0, acc[0][0]);           \
    acc[1][0] = MFMA_MX(a1, B0, acc[1][0]);           \
    acc[0][1] = MFMA_MX(a0, B1, acc[0][1]);           \
    acc[1][1] = MFMA_MX(a1, B1, acc[1][1]);           \
    __builtin_amdgcn_s_setprio(0); } while (0)
#define P2(B0, B1) do {                               \
    __builtin_amdgcn_s_setprio(1);                    \
    acc[2][0] = MFMA_MX(a2, B0, acc[2][0]);           \
    acc[3][0] = MFMA_MX(a3, B0, acc[3][0]);           \
    acc[2][1] = MFMA_MX(a2, B1, acc[2][1]);           \
    acc[3][1] = MFMA_MX(a3, B1, acc[3][1]);           \
    __builtin_amdgcn_s_setprio(0); } while (0)

__global__ __launch_bounds__(256, 2) void fp8lin_gemm(
    const uint8_t* __restrict__ Apack,
    const uint8_t* __restrict__ Bpack,
    const unsigned* __restrict__ amax_bits,
    const float* __restrict__ wscale,
    const float* __restrict__ bias,
    float* __restrict__ out,
    int M, int N, int K) {
    const int tid = threadIdx.x;
    const int wid = tid >> 6;
    const int lane = tid & 63;
    const int wm = wid >> 1;   // 0..1
    const int wn = wid & 1;    // 0..1

    // ---- bijective XCD swizzle ----
    const int nbx = gridDim.x;                       // 128
    const int orig = blockIdx.y * nbx + blockIdx.x;
    const int cpx = (gridDim.x * gridDim.y) >> 3;    // 512
    const int swzb = (orig & 7) * cpx + (orig >> 3);
    const int brow = (swzb / nbx) * BM;
    const int bcol = (swzb % nbx) * BN;

    const int NKT = K >> 6;
    const size_t TSTRIDE = (size_t)NKT * 2048;
    const int mt0 = (brow >> 5) + wm * 4;
    const uint8_t* uA0 = Apack + (size_t)(mt0 + 0) * TSTRIDE;
    const uint8_t* uA1 = Apack + (size_t)(mt0 + 1) * TSTRIDE;
    const uint8_t* uA2 = Apack + (size_t)(mt0 + 2) * TSTRIDE;
    const uint8_t* uA3 = Apack + (size_t)(mt0 + 3) * TSTRIDE;
    const uint8_t* uB0 = Bpack + (size_t)((bcol >> 5) + wn * 2) * TSTRIDE;
    const uint8_t* uB1 = uB0 + TSTRIDE;
    const int voff = lane * 32;

    f32x16 acc[4][2];
#pragma unroll
    for (int mi = 0; mi < 4; ++mi)
#pragma unroll
        for (int ni = 0; ni < 2; ++ni)
#pragma unroll
            for (int r = 0; r < 16; ++r) acc[mi][ni][r] = 0.0f;

    i32x8 a0, a1, a2, a3, bE0, bE1, bO0, bO1;   // static names (rule #20)

    // ---- prologue: queue = [bE(0), a0a1(0), a2a3(0), bO(1)] = 16 outstanding
    LDU(bE0, uB0, 0); LDU(bE1, uB1, 0);
    LDU(a0, uA0, 0);  LDU(a1, uA1, 0);
    LDU(a2, uA2, 0);  LDU(a3, uA3, 0);
    LDU(bO0, uB0, 1); LDU(bO1, uB1, 1);

    const int NT = K / BK;  // 64 (even)
#pragma unroll 1
    for (int tp = 0; tp < NT; tp += 2) {
        // ===== even tile tp (B = E set) =====
        WAITVM(8);                       // retire bE(tp) + a0a1(tp)
        P1(bE0, bE1);
        LDU(a0, uA0, tp + 1); LDU(a1, uA1, tp + 1);
        WAITVM(8);                       // retire a2a3(tp)
        P2(bE0, bE1);
        LDU(a2, uA2, tp + 1); LDU(a3, uA3, tp + 1);
        if (tp + 2 < NT) {
            LDU(bE0, uB0, tp + 2); LDU(bE1, uB1, tp + 2);
            // ===== odd tile tp+1 (B = O set) =====
            WAITVM(8);
            P1(bO0, bO1);
            LDU(a0, uA0, tp + 2); LDU(a1, uA1, tp + 2);
            WAITVM(8);
            P2(bO0, bO1);
            LDU(a2, uA2, tp + 2); LDU(a3, uA3, tp + 2);
            LDU(bO0, uB0, tp + 3); LDU(bO1, uB1, tp + 3);
        } else {
            WAITVM(4);
            P1(bO0, bO1);
            WAITVM(0);
            P2(bO0, bO1);
        }
    }

    // ---- epilogue: 32x32 C/D layout col=lane&31, row=(reg&3)+8*(reg>>2)+4*q ----
    // PLAIN stores (A/B vs R15): let L2 aggregate full lines; each store instr
    // writes two aligned 128B line segments (32 cols x 2 rows).
    float s = (fmaxf(__uint_as_float(*amax_bits), 1e-12f) / FP8_MAX_V) * wscale[0];
    const int l31 = lane & 31;
    const int q = lane >> 5;
    const int colg = bcol + wn * 64 + l31;
    const int rowg0 = brow + wm * 128 + 4 * q;
#pragma unroll
    for (int ni = 0; ni < 2; ++ni) {
        int col = colg + ni * 32;
        float bv = bias[col];
#pragma unroll
        for (int mi = 0; mi < 4; ++mi) {
            int rb = rowg0 + mi * 32;
#pragma unroll
            for (int reg = 0; reg < 16; ++reg) {
                int row = rb + (reg & 3) + 8 * (reg >> 2);
                out[(size_t)row * N + col] = acc[mi][ni][reg] * s + bv;
            }
        }
    }
}

extern "C" void kernel_launch(void* const* d_in, const int* in_sizes, int n_in,
                              void* d_out, int out_size, void* d_ws, size_t ws_size,
                              hipStream_t stream) {
    const float* x = (const float*)d_in[0];
    const void* w = d_in[1];
    const float* wscale = (const float*)d_in[2];
    const float* bias = (const float*)d_in[3];
    float* out = (float*)d_out;

    const int Bb = 4, S = 2048, K = 4096, N = 16384;
    const int M = Bb * S;
    const long nx = (long)M * K;

    unsigned* amax_bits = (unsigned*)d_ws;
    unsigned* wflag = (unsigned*)((char*)d_ws + 32);
    uint8_t* apack = (uint8_t*)((char*)d_ws + 256);
    uint8_t* bpack = (uint8_t*)((char*)d_ws + 256 + nx);

    fp8lin_probe<<<1, 256, 0, stream>>>((const uint32_t*)w, wflag, amax_bits);
    fp8lin_amax<<<2048, 256, 0, stream>>>((const float4*)x, amax_bits, nx / 4);
    fp8lin_quantpack<<<2048, 256, 0, stream>>>(x, amax_bits, (uchar4*)apack, M, K);
    fp8lin_packw<<<2048, 256, 0, stream>>>(w, wflag, bpack, N, K);

    dim3 grid(N / BN, M / BM);   // (128, 32) = 4096 blocks
    fp8lin_gemm<<<grid, 256, 0, stream>>>(apack, bpack, amax_bits, wscale, bias, out, M, N, K);
}